// Round 1
// baseline (2527.474 us; speedup 1.0000x reference)
//
#include <hip/hip_runtime.h>

// Problem constants (match reference)
#define NPB 16          // nodes per block in projection kernel

// ---------------------------------------------------------------------------
// Kernel 1: per-node projections q_inv,k_inv,v_inv (4 heads x 60) and
// q_ev,k_ev (3 heads x 80). One block = 16 nodes, 1024 threads.
// Thread t: node = t/64, slot = t%64 (slots 0..59 active, each slot = 4
// consecutive output columns). W loads are coalesced float4, L2-hot.
// ---------------------------------------------------------------------------
__global__ __launch_bounds__(1024) void proj_kernel(
    const float* __restrict__ x,
    const float* __restrict__ Wq, const float* __restrict__ Wk,
    const float* __restrict__ Wv,
    const float* __restrict__ Wqe, const float* __restrict__ Wke,
    float* __restrict__ q_inv, float* __restrict__ k_inv,
    float* __restrict__ v_inv,
    float* __restrict__ q_ev, float* __restrict__ k_ev, int N)
{
    __shared__ float xs[NPB * 240];
    const int base_node = blockIdx.x * NPB;
    for (int idx = threadIdx.x; idx < NPB * 240; idx += 1024) {
        int g = base_node * 240 + idx;
        xs[idx] = (g < N * 240) ? x[g] : 0.f;
    }
    __syncthreads();

    const int nl   = threadIdx.x >> 6;   // 0..15 local node
    const int slot = threadIdx.x & 63;   // 0..63
    const int node = base_node + nl;
    if (slot >= 60 || node >= N) return;

    const int hi  = slot / 15;           // inv head (slot*4/60)
    const int jdi = slot * 4 - hi * 60;  // inv col within head
    const int he  = slot / 20;           // ev head (slot*4/80)
    const int jde = slot * 4 - he * 80;

    const float* xrow = &xs[nl * 240];

    float4 aq = {0.f,0.f,0.f,0.f}, ak = aq, av = aq;
    {
        const float* wq = Wq + hi * 3600 + jdi;
        const float* wk = Wk + hi * 3600 + jdi;
        const float* wv = Wv + hi * 3600 + jdi;
        const float* xr = xrow + hi * 60;
        #pragma unroll 4
        for (int i = 0; i < 60; ++i) {
            float xv = xr[i];
            float4 w;
            w = *(const float4*)&wq[i * 60];
            aq.x += xv * w.x; aq.y += xv * w.y; aq.z += xv * w.z; aq.w += xv * w.w;
            w = *(const float4*)&wk[i * 60];
            ak.x += xv * w.x; ak.y += xv * w.y; ak.z += xv * w.z; ak.w += xv * w.w;
            w = *(const float4*)&wv[i * 60];
            av.x += xv * w.x; av.y += xv * w.y; av.z += xv * w.z; av.w += xv * w.w;
        }
    }
    float4 aqe = {0.f,0.f,0.f,0.f}, ake = aqe;
    {
        const float* wq = Wqe + he * 6400 + jde;
        const float* wk = Wke + he * 6400 + jde;
        const float* xr = xrow + he * 80;
        #pragma unroll 4
        for (int i = 0; i < 80; ++i) {
            float xv = xr[i];
            float4 w;
            w = *(const float4*)&wq[i * 80];
            aqe.x += xv * w.x; aqe.y += xv * w.y; aqe.z += xv * w.z; aqe.w += xv * w.w;
            w = *(const float4*)&wk[i * 80];
            ake.x += xv * w.x; ake.y += xv * w.y; ake.z += xv * w.z; ake.w += xv * w.w;
        }
    }
    const int ob = node * 240 + slot * 4;
    *(float4*)&q_inv[ob] = aq;
    *(float4*)&k_inv[ob] = ak;
    *(float4*)&v_inv[ob] = av;
    *(float4*)&q_ev[ob]  = aqe;
    *(float4*)&k_ev[ob]  = ake;
}

// ---------------------------------------------------------------------------
// Kernel 2: one thread per edge. Filter weights (35x240 fp32, both) + biases
// staged in LDS (69 KB -> 2 blocks/CU). All W reads are wave-uniform
// broadcast ds_read_b128 with immediate offsets (k*960B < 64KB).
// Scatter via global fp32 atomics.
// ---------------------------------------------------------------------------
__global__ __launch_bounds__(256) void edge_kernel(
    const float* __restrict__ ev_f, const float* __restrict__ rbf,
    const float* __restrict__ sh,   const float* __restrict__ cut,
    const float* __restrict__ Wfi,  const float* __restrict__ bfi,
    const float* __restrict__ Wfe,  const float* __restrict__ bfe,
    const int* __restrict__ snd,    const int* __restrict__ rcv,
    const float* __restrict__ q_inv, const float* __restrict__ k_inv,
    const float* __restrict__ v_inv,
    const float* __restrict__ q_ev,  const float* __restrict__ k_ev,
    float* __restrict__ dinv, float* __restrict__ dev, int E)
{
    __shared__ float WI[35 * 240];
    __shared__ float WE[35 * 240];
    __shared__ float BI[240];
    __shared__ float BE[240];
    for (int idx = threadIdx.x; idx < 35 * 240; idx += 256) {
        WI[idx] = Wfi[idx];
        WE[idx] = Wfe[idx];
    }
    for (int idx = threadIdx.x; idx < 240; idx += 256) {
        BI[idx] = bfi[idx];
        BE[idx] = bfe[idx];
    }
    __syncthreads();

    const float s60 = 0.12909944487358056f;  // 1/sqrt(60)
    const float s80 = 0.11180339887498948f;  // 1/sqrt(80)
    const int stride = gridDim.x * blockDim.x;

    for (int e = blockIdx.x * blockDim.x + threadIdx.x; e < E; e += stride) {
        const int s = snd[e], r = rcv[e];

        float f[35];
        {
            const float4* rb = (const float4*)(rbf + (size_t)e * 32);
            #pragma unroll
            for (int k4 = 0; k4 < 8; ++k4) {
                float4 t = rb[k4];
                f[k4 * 4 + 0] = t.x; f[k4 * 4 + 1] = t.y;
                f[k4 * 4 + 2] = t.z; f[k4 * 4 + 3] = t.w;
            }
            const float* es = ev_f + (size_t)s * 15;
            const float* er = ev_f + (size_t)r * 15;
            float i0 = 0.f, i1 = 0.f, i2 = 0.f;
            #pragma unroll
            for (int i = 0; i < 3; ++i)  { float d = es[i] - er[i]; i0 += d * d; }
            #pragma unroll
            for (int i = 3; i < 8; ++i)  { float d = es[i] - er[i]; i1 += d * d; }
            #pragma unroll
            for (int i = 8; i < 15; ++i) { float d = es[i] - er[i]; i2 += d * d; }
            f[32] = i0; f[33] = i1; f[34] = i2;
        }
        const float c = cut[e];

        // ---- invariant attention logits: alpha_inv[h] ----
        float aI[4];
        {
            const float4* qb = (const float4*)(q_inv + (size_t)r * 240);
            const float4* kb = (const float4*)(k_inv + (size_t)s * 240);
            #pragma unroll
            for (int h = 0; h < 4; ++h) {
                float acc = 0.f;
                #pragma unroll 1
                for (int j4 = 0; j4 < 15; ++j4) {
                    const int j = h * 60 + j4 * 4;
                    float4 fw = *(const float4*)&BI[j];
                    #pragma unroll
                    for (int k = 0; k < 35; ++k) {
                        const float4 w = *(const float4*)&WI[k * 240 + j];
                        fw.x += f[k] * w.x; fw.y += f[k] * w.y;
                        fw.z += f[k] * w.z; fw.w += f[k] * w.w;
                    }
                    const float4 q = qb[h * 15 + j4];
                    const float4 kk = kb[h * 15 + j4];
                    acc += q.x * kk.x * fw.x + q.y * kk.y * fw.y
                         + q.z * kk.z * fw.z + q.w * kk.w * fw.w;
                }
                aI[h] = acc * s60 * c;
            }
        }

        // ---- equivariant attention logits: alpha_ev[h] ----
        float aE[3];
        {
            const float4* qb = (const float4*)(q_ev + (size_t)r * 240);
            const float4* kb = (const float4*)(k_ev + (size_t)s * 240);
            #pragma unroll
            for (int h = 0; h < 3; ++h) {
                float acc = 0.f;
                #pragma unroll 1
                for (int j4 = 0; j4 < 20; ++j4) {
                    const int j = h * 80 + j4 * 4;
                    float4 fw = *(const float4*)&BE[j];
                    #pragma unroll
                    for (int k = 0; k < 35; ++k) {
                        const float4 w = *(const float4*)&WE[k * 240 + j];
                        fw.x += f[k] * w.x; fw.y += f[k] * w.y;
                        fw.z += f[k] * w.z; fw.w += f[k] * w.w;
                    }
                    const float4 q = qb[h * 20 + j4];
                    const float4 kk = kb[h * 20 + j4];
                    acc += q.x * kk.x * fw.x + q.y * kk.y * fw.y
                         + q.z * kk.z * fw.z + q.w * kk.w * fw.w;
                }
                aE[h] = acc * s80 * c;
            }
        }

        // ---- scatter d_inv += alpha_inv * v_inv[sender] ----
        {
            const float4* vb = (const float4*)(v_inv + (size_t)s * 240);
            float* dr = dinv + (size_t)r * 240;
            #pragma unroll
            for (int h = 0; h < 4; ++h) {
                const float sc = aI[h];
                #pragma unroll 1
                for (int j4 = 0; j4 < 15; ++j4) {
                    const float4 v = vb[h * 15 + j4];
                    const int j = h * 60 + j4 * 4;
                    atomicAdd(&dr[j + 0], sc * v.x);
                    atomicAdd(&dr[j + 1], sc * v.y);
                    atomicAdd(&dr[j + 2], sc * v.z);
                    atomicAdd(&dr[j + 3], sc * v.w);
                }
            }
        }
        // ---- scatter d_ev += alpha_ev(repeated) * sh ----
        {
            const float* she = sh + (size_t)e * 15;
            float* de = dev + (size_t)r * 15;
            #pragma unroll
            for (int i = 0; i < 15; ++i) {
                const float a = (i < 3) ? aE[0] : ((i < 8) ? aE[1] : aE[2]);
                atomicAdd(&de[i], a * she[i]);
            }
        }
    }
}

extern "C" void kernel_launch(void* const* d_in, const int* in_sizes, int n_in,
                              void* d_out, int out_size, void* d_ws, size_t ws_size,
                              hipStream_t stream) {
    const float* inv_f = (const float*)d_in[0];
    const float* ev_f  = (const float*)d_in[1];
    const float* rbf   = (const float*)d_in[2];
    const float* sh    = (const float*)d_in[3];
    const float* cut   = (const float*)d_in[4];
    const float* Wq    = (const float*)d_in[5];
    const float* Wk    = (const float*)d_in[6];
    const float* Wv    = (const float*)d_in[7];
    const float* Wqe   = (const float*)d_in[8];
    const float* Wke   = (const float*)d_in[9];
    const float* Wfi   = (const float*)d_in[10];
    const float* bfi   = (const float*)d_in[11];
    const float* Wfe   = (const float*)d_in[12];
    const float* bfe   = (const float*)d_in[13];
    const int*   snd   = (const int*)d_in[14];
    const int*   rcv   = (const int*)d_in[15];

    const int N = in_sizes[0] / 240;
    const int E = in_sizes[14];

    float* out  = (float*)d_out;
    float* dinv = out;                       // [N,240]
    float* dev  = out + (size_t)N * 240;     // [N,15]

    float* ws = (float*)d_ws;
    const size_t Nf = (size_t)N * 240;
    float* q_inv = ws + 0 * Nf;
    float* k_inv = ws + 1 * Nf;
    float* v_inv = ws + 2 * Nf;
    float* q_ev  = ws + 3 * Nf;
    float* k_ev  = ws + 4 * Nf;

    hipMemsetAsync(d_out, 0, (size_t)out_size * sizeof(float), stream);

    proj_kernel<<<(N + NPB - 1) / NPB, 1024, 0, stream>>>(
        inv_f, Wq, Wk, Wv, Wqe, Wke, q_inv, k_inv, v_inv, q_ev, k_ev, N);

    edge_kernel<<<512, 256, 0, stream>>>(
        ev_f, rbf, sh, cut, Wfi, bfi, Wfe, bfe, snd, rcv,
        q_inv, k_inv, v_inv, q_ev, k_ev, dinv, dev, E);
}

// Round 2
// 511.607 us; speedup vs baseline: 4.9403x; 4.9403x over previous
//
#include <hip/hip_runtime.h>

#define PNPB 16   // nodes per proj block (4 waves x 4 nodes)

// ---------------------------------------------------------------------------
// Projection kernel: q_inv,k_inv,v_inv (4h x 60) and q_ev,k_ev (3h x 80).
// 256 threads: slot = t&63 (4 output cols), node-group = t>>6 (4 nodes each).
// Each W float4 load is reused for 4 nodes -> 4x less L2 W traffic.
// ---------------------------------------------------------------------------
__global__ __launch_bounds__(256) void proj_kernel(
    const float* __restrict__ x,
    const float* __restrict__ Wq, const float* __restrict__ Wk,
    const float* __restrict__ Wv,
    const float* __restrict__ Wqe, const float* __restrict__ Wke,
    float* __restrict__ q_inv, float* __restrict__ k_inv,
    float* __restrict__ v_inv,
    float* __restrict__ q_ev, float* __restrict__ k_ev, int N)
{
    __shared__ float xs[PNPB * 240];
    const int base_node = blockIdx.x * PNPB;
    for (int idx = threadIdx.x; idx < PNPB * 240; idx += 256) {
        int g = base_node * 240 + idx;
        xs[idx] = (g < N * 240) ? x[g] : 0.f;
    }
    __syncthreads();

    const int slot = threadIdx.x & 63;   // 0..63
    const int wg   = threadIdx.x >> 6;   // 0..3 -> nodes wg*4 .. wg*4+3
    if (slot >= 60) return;

    const int hi  = slot / 15;           // inv head
    const int jdi = slot * 4 - hi * 60;
    const int he  = slot / 20;           // ev head
    const int jde = slot * 4 - he * 80;
    const int nl0 = wg * 4;

    float4 aq[4], ak[4], av[4], aqe[4], ake[4];
    #pragma unroll
    for (int n = 0; n < 4; ++n) {
        aq[n] = make_float4(0.f,0.f,0.f,0.f); ak[n] = aq[n]; av[n] = aq[n];
        aqe[n] = aq[n]; ake[n] = aq[n];
    }

    {
        const float* wq = Wq + hi * 3600 + jdi;
        const float* wk = Wk + hi * 3600 + jdi;
        const float* wv = Wv + hi * 3600 + jdi;
        const float* xb = &xs[nl0 * 240 + hi * 60];
        #pragma unroll 2
        for (int i = 0; i < 60; ++i) {
            float xv0 = xb[i], xv1 = xb[240 + i], xv2 = xb[480 + i], xv3 = xb[720 + i];
            float4 w;
            w = *(const float4*)&wq[i * 60];
            aq[0].x += xv0*w.x; aq[0].y += xv0*w.y; aq[0].z += xv0*w.z; aq[0].w += xv0*w.w;
            aq[1].x += xv1*w.x; aq[1].y += xv1*w.y; aq[1].z += xv1*w.z; aq[1].w += xv1*w.w;
            aq[2].x += xv2*w.x; aq[2].y += xv2*w.y; aq[2].z += xv2*w.z; aq[2].w += xv2*w.w;
            aq[3].x += xv3*w.x; aq[3].y += xv3*w.y; aq[3].z += xv3*w.z; aq[3].w += xv3*w.w;
            w = *(const float4*)&wk[i * 60];
            ak[0].x += xv0*w.x; ak[0].y += xv0*w.y; ak[0].z += xv0*w.z; ak[0].w += xv0*w.w;
            ak[1].x += xv1*w.x; ak[1].y += xv1*w.y; ak[1].z += xv1*w.z; ak[1].w += xv1*w.w;
            ak[2].x += xv2*w.x; ak[2].y += xv2*w.y; ak[2].z += xv2*w.z; ak[2].w += xv2*w.w;
            ak[3].x += xv3*w.x; ak[3].y += xv3*w.y; ak[3].z += xv3*w.z; ak[3].w += xv3*w.w;
            w = *(const float4*)&wv[i * 60];
            av[0].x += xv0*w.x; av[0].y += xv0*w.y; av[0].z += xv0*w.z; av[0].w += xv0*w.w;
            av[1].x += xv1*w.x; av[1].y += xv1*w.y; av[1].z += xv1*w.z; av[1].w += xv1*w.w;
            av[2].x += xv2*w.x; av[2].y += xv2*w.y; av[2].z += xv2*w.z; av[2].w += xv2*w.w;
            av[3].x += xv3*w.x; av[3].y += xv3*w.y; av[3].z += xv3*w.z; av[3].w += xv3*w.w;
        }
    }
    {
        const float* wq = Wqe + he * 6400 + jde;
        const float* wk = Wke + he * 6400 + jde;
        const float* xb = &xs[nl0 * 240 + he * 80];
        #pragma unroll 2
        for (int i = 0; i < 80; ++i) {
            float xv0 = xb[i], xv1 = xb[240 + i], xv2 = xb[480 + i], xv3 = xb[720 + i];
            float4 w;
            w = *(const float4*)&wq[i * 80];
            aqe[0].x += xv0*w.x; aqe[0].y += xv0*w.y; aqe[0].z += xv0*w.z; aqe[0].w += xv0*w.w;
            aqe[1].x += xv1*w.x; aqe[1].y += xv1*w.y; aqe[1].z += xv1*w.z; aqe[1].w += xv1*w.w;
            aqe[2].x += xv2*w.x; aqe[2].y += xv2*w.y; aqe[2].z += xv2*w.z; aqe[2].w += xv2*w.w;
            aqe[3].x += xv3*w.x; aqe[3].y += xv3*w.y; aqe[3].z += xv3*w.z; aqe[3].w += xv3*w.w;
            w = *(const float4*)&wk[i * 80];
            ake[0].x += xv0*w.x; ake[0].y += xv0*w.y; ake[0].z += xv0*w.z; ake[0].w += xv0*w.w;
            ake[1].x += xv1*w.x; ake[1].y += xv1*w.y; ake[1].z += xv1*w.z; ake[1].w += xv1*w.w;
            ake[2].x += xv2*w.x; ake[2].y += xv2*w.y; ake[2].z += xv2*w.z; ake[2].w += xv2*w.w;
            ake[3].x += xv3*w.x; ake[3].y += xv3*w.y; ake[3].z += xv3*w.z; ake[3].w += xv3*w.w;
        }
    }
    #pragma unroll
    for (int n = 0; n < 4; ++n) {
        const int node = base_node + nl0 + n;
        if (node >= N) break;
        const int ob = node * 240 + slot * 4;
        *(float4*)&q_inv[ob] = aq[n];
        *(float4*)&k_inv[ob] = ak[n];
        *(float4*)&v_inv[ob] = av[n];
        *(float4*)&q_ev[ob]  = aqe[n];
        *(float4*)&k_ev[ob]  = ake[n];
    }
}

// ---------------------------------------------------------------------------
// CSR build: histogram -> 1-block scan -> scatter
// ---------------------------------------------------------------------------
__global__ __launch_bounds__(256) void hist_kernel(
    const int* __restrict__ rcv, int* __restrict__ counts, int E)
{
    int e = blockIdx.x * 256 + threadIdx.x;
    if (e < E) atomicAdd(&counts[rcv[e]], 1);
}

__global__ __launch_bounds__(1024) void scan_kernel(
    const int* __restrict__ counts, int* __restrict__ rowstart,
    int* __restrict__ cursor, int N)
{
    __shared__ int s[1024];
    __shared__ int carry;
    if (threadIdx.x == 0) carry = 0;
    __syncthreads();
    for (int base = 0; base < N; base += 1024) {
        const int i = base + threadIdx.x;
        int v = (i < N) ? counts[i] : 0;
        s[threadIdx.x] = v;
        __syncthreads();
        for (int off = 1; off < 1024; off <<= 1) {
            int t = (threadIdx.x >= off) ? s[threadIdx.x - off] : 0;
            __syncthreads();
            s[threadIdx.x] += t;
            __syncthreads();
        }
        if (i < N) {
            int ex = carry + s[threadIdx.x] - v;
            rowstart[i] = ex;
            cursor[i] = ex;
        }
        __syncthreads();
        if (threadIdx.x == 1023) carry += s[1023];
        __syncthreads();
    }
    if (threadIdx.x == 0) rowstart[N] = carry;
}

__global__ __launch_bounds__(256) void scatter_kernel(
    const int* __restrict__ rcv, int* __restrict__ cursor,
    int* __restrict__ csr, int E)
{
    int e = blockIdx.x * 256 + threadIdx.x;
    if (e < E) {
        int pos = atomicAdd(&cursor[rcv[e]], 1);
        csr[pos] = e;
    }
}

// ---------------------------------------------------------------------------
// Edge alpha kernel: per-edge filter matmuls + attention logits.
// Writes 8 floats/edge (cutoff folded in): aI[4], aE[3], pad.
// Filter weights in LDS; all W reads wave-uniform broadcast.
// ---------------------------------------------------------------------------
__global__ __launch_bounds__(256) void alpha_kernel(
    const float* __restrict__ ev_f, const float* __restrict__ rbf,
    const float* __restrict__ cut,
    const float* __restrict__ Wfi,  const float* __restrict__ bfi,
    const float* __restrict__ Wfe,  const float* __restrict__ bfe,
    const int* __restrict__ snd,    const int* __restrict__ rcv,
    const float* __restrict__ q_inv, const float* __restrict__ k_inv,
    const float* __restrict__ q_ev,  const float* __restrict__ k_ev,
    float* __restrict__ alpha, int E)
{
    __shared__ float WI[35 * 240];
    __shared__ float WE[35 * 240];
    __shared__ float BI[240];
    __shared__ float BE[240];
    for (int idx = threadIdx.x; idx < 35 * 240; idx += 256) {
        WI[idx] = Wfi[idx];
        WE[idx] = Wfe[idx];
    }
    for (int idx = threadIdx.x; idx < 240; idx += 256) {
        BI[idx] = bfi[idx];
        BE[idx] = bfe[idx];
    }
    __syncthreads();

    const float s60 = 0.12909944487358056f;  // 1/sqrt(60)
    const float s80 = 0.11180339887498948f;  // 1/sqrt(80)

    const int e = blockIdx.x * 256 + threadIdx.x;
    if (e >= E) return;

    const int s = snd[e], r = rcv[e];

    float f[35];
    {
        const float4* rb = (const float4*)(rbf + (size_t)e * 32);
        #pragma unroll
        for (int k4 = 0; k4 < 8; ++k4) {
            float4 t = rb[k4];
            f[k4 * 4 + 0] = t.x; f[k4 * 4 + 1] = t.y;
            f[k4 * 4 + 2] = t.z; f[k4 * 4 + 3] = t.w;
        }
        const float* es = ev_f + (size_t)s * 15;
        const float* er = ev_f + (size_t)r * 15;
        float i0 = 0.f, i1 = 0.f, i2 = 0.f;
        #pragma unroll
        for (int i = 0; i < 3; ++i)  { float d = es[i] - er[i]; i0 += d * d; }
        #pragma unroll
        for (int i = 3; i < 8; ++i)  { float d = es[i] - er[i]; i1 += d * d; }
        #pragma unroll
        for (int i = 8; i < 15; ++i) { float d = es[i] - er[i]; i2 += d * d; }
        f[32] = i0; f[33] = i1; f[34] = i2;
    }
    const float c = cut[e];

    float out[8];
    {
        const float4* qb = (const float4*)(q_inv + (size_t)r * 240);
        const float4* kb = (const float4*)(k_inv + (size_t)s * 240);
        #pragma unroll
        for (int h = 0; h < 4; ++h) {
            float acc = 0.f;
            #pragma unroll 1
            for (int j4 = 0; j4 < 15; ++j4) {
                const int j = h * 60 + j4 * 4;
                float4 fw = *(const float4*)&BI[j];
                #pragma unroll
                for (int k = 0; k < 35; ++k) {
                    const float4 w = *(const float4*)&WI[k * 240 + j];
                    fw.x += f[k] * w.x; fw.y += f[k] * w.y;
                    fw.z += f[k] * w.z; fw.w += f[k] * w.w;
                }
                const float4 q = qb[h * 15 + j4];
                const float4 kk = kb[h * 15 + j4];
                acc += q.x * kk.x * fw.x + q.y * kk.y * fw.y
                     + q.z * kk.z * fw.z + q.w * kk.w * fw.w;
            }
            out[h] = acc * s60 * c;
        }
    }
    {
        const float4* qb = (const float4*)(q_ev + (size_t)r * 240);
        const float4* kb = (const float4*)(k_ev + (size_t)s * 240);
        #pragma unroll
        for (int h = 0; h < 3; ++h) {
            float acc = 0.f;
            #pragma unroll 1
            for (int j4 = 0; j4 < 20; ++j4) {
                const int j = h * 80 + j4 * 4;
                float4 fw = *(const float4*)&BE[j];
                #pragma unroll
                for (int k = 0; k < 35; ++k) {
                    const float4 w = *(const float4*)&WE[k * 240 + j];
                    fw.x += f[k] * w.x; fw.y += f[k] * w.y;
                    fw.z += f[k] * w.z; fw.w += f[k] * w.w;
                }
                const float4 q = qb[h * 20 + j4];
                const float4 kk = kb[h * 20 + j4];
                acc += q.x * kk.x * fw.x + q.y * kk.y * fw.y
                     + q.z * kk.z * fw.z + q.w * kk.w * fw.w;
            }
            out[4 + h] = acc * s80 * c;
        }
    }
    out[7] = 0.f;
    float4* ap = (float4*)(alpha + (size_t)e * 8);
    ap[0] = make_float4(out[0], out[1], out[2], out[3]);
    ap[1] = make_float4(out[4], out[5], out[6], out[7]);
}

// ---------------------------------------------------------------------------
// Gather kernel: one block per receiver node; thread = output column.
// No atomics; writes every output element exactly once.
// ---------------------------------------------------------------------------
__global__ __launch_bounds__(256) void gather_kernel(
    const int* __restrict__ rowstart, const int* __restrict__ csr,
    const int* __restrict__ snd, const float* __restrict__ alpha,
    const float* __restrict__ v_inv, const float* __restrict__ sh,
    float* __restrict__ dinv, float* __restrict__ dev)
{
    const int r = blockIdx.x;
    const int c = threadIdx.x;
    const int beg = rowstart[r], end = rowstart[r + 1];

    if (c < 240) {
        const int h = c / 60;
        float acc = 0.f;
        for (int idx = beg; idx < end; ++idx) {
            const int e = csr[idx];
            const int s = snd[e];
            acc += alpha[(size_t)e * 8 + h] * v_inv[(size_t)s * 240 + c];
        }
        dinv[(size_t)r * 240 + c] = acc;
    } else if (c < 255) {
        const int i = c - 240;
        const int h = (i < 3) ? 4 : ((i < 8) ? 5 : 6);
        float acc = 0.f;
        for (int idx = beg; idx < end; ++idx) {
            const int e = csr[idx];
            acc += alpha[(size_t)e * 8 + h] * sh[(size_t)e * 15 + i];
        }
        dev[(size_t)r * 15 + i] = acc;
    }
}

extern "C" void kernel_launch(void* const* d_in, const int* in_sizes, int n_in,
                              void* d_out, int out_size, void* d_ws, size_t ws_size,
                              hipStream_t stream) {
    const float* inv_f = (const float*)d_in[0];
    const float* ev_f  = (const float*)d_in[1];
    const float* rbf   = (const float*)d_in[2];
    const float* sh    = (const float*)d_in[3];
    const float* cut   = (const float*)d_in[4];
    const float* Wq    = (const float*)d_in[5];
    const float* Wk    = (const float*)d_in[6];
    const float* Wv    = (const float*)d_in[7];
    const float* Wqe   = (const float*)d_in[8];
    const float* Wke   = (const float*)d_in[9];
    const float* Wfi   = (const float*)d_in[10];
    const float* bfi   = (const float*)d_in[11];
    const float* Wfe   = (const float*)d_in[12];
    const float* bfe   = (const float*)d_in[13];
    const int*   snd   = (const int*)d_in[14];
    const int*   rcv   = (const int*)d_in[15];

    const int N = in_sizes[0] / 240;
    const int E = in_sizes[14];

    float* out  = (float*)d_out;
    float* dinv = out;                       // [N,240]
    float* dev  = out + (size_t)N * 240;     // [N,15]

    // workspace layout
    float* ws = (float*)d_ws;
    const size_t Nf = (size_t)N * 240;
    float* q_inv = ws + 0 * Nf;
    float* k_inv = ws + 1 * Nf;
    float* v_inv = ws + 2 * Nf;
    float* q_ev  = ws + 3 * Nf;
    float* k_ev  = ws + 4 * Nf;
    float* alpha = ws + 5 * Nf;                          // E*8 floats
    int*   ibase = (int*)(alpha + (size_t)E * 8);
    int*   counts   = ibase;                              // N
    int*   rowstart = ibase + N;                          // N+1
    int*   cursor   = ibase + 2 * N + 1;                  // N
    int*   csr      = ibase + 3 * N + 1;                  // E

    hipMemsetAsync(counts, 0, (size_t)N * sizeof(int), stream);

    proj_kernel<<<(N + PNPB - 1) / PNPB, 256, 0, stream>>>(
        inv_f, Wq, Wk, Wv, Wqe, Wke, q_inv, k_inv, v_inv, q_ev, k_ev, N);

    const int eb = (E + 255) / 256;
    hist_kernel<<<eb, 256, 0, stream>>>(rcv, counts, E);
    scan_kernel<<<1, 1024, 0, stream>>>(counts, rowstart, cursor, N);
    scatter_kernel<<<eb, 256, 0, stream>>>(rcv, cursor, csr, E);

    alpha_kernel<<<eb, 256, 0, stream>>>(
        ev_f, rbf, cut, Wfi, bfi, Wfe, bfe, snd, rcv,
        q_inv, k_inv, q_ev, k_ev, alpha, E);

    gather_kernel<<<N, 256, 0, stream>>>(
        rowstart, csr, snd, alpha, v_inv, sh, dinv, dev);
}

// Round 3
// 401.534 us; speedup vs baseline: 6.2946x; 1.2741x over previous
//
#include <hip/hip_runtime.h>

#define PNPB 16   // nodes per proj block
#define ABLK 128  // alpha block threads
#define EPT  4    // edges per thread in alpha

// ---------------------------------------------------------------------------
// Projection kernel: q_inv,k_inv,v_inv (4h x 60) and q_ev,k_ev (3h x 80).
// 256 threads: slot = t&63 (4 output cols), node-group = t>>6 (4 nodes each).
// ---------------------------------------------------------------------------
__global__ __launch_bounds__(256) void proj_kernel(
    const float* __restrict__ x,
    const float* __restrict__ Wq, const float* __restrict__ Wk,
    const float* __restrict__ Wv,
    const float* __restrict__ Wqe, const float* __restrict__ Wke,
    float* __restrict__ q_inv, float* __restrict__ k_inv,
    float* __restrict__ v_inv,
    float* __restrict__ q_ev, float* __restrict__ k_ev, int N)
{
    __shared__ float xs[PNPB * 240];
    const int base_node = blockIdx.x * PNPB;
    for (int idx = threadIdx.x; idx < PNPB * 240; idx += 256) {
        int g = base_node * 240 + idx;
        xs[idx] = (g < N * 240) ? x[g] : 0.f;
    }
    __syncthreads();

    const int slot = threadIdx.x & 63;
    const int wg   = threadIdx.x >> 6;
    if (slot >= 60) return;

    const int hi  = slot / 15;
    const int jdi = slot * 4 - hi * 60;
    const int he  = slot / 20;
    const int jde = slot * 4 - he * 80;
    const int nl0 = wg * 4;

    float4 aq[4], ak[4], av[4], aqe[4], ake[4];
    #pragma unroll
    for (int n = 0; n < 4; ++n) {
        aq[n] = make_float4(0.f,0.f,0.f,0.f); ak[n] = aq[n]; av[n] = aq[n];
        aqe[n] = aq[n]; ake[n] = aq[n];
    }
    {
        const float* wq = Wq + hi * 3600 + jdi;
        const float* wk = Wk + hi * 3600 + jdi;
        const float* wv = Wv + hi * 3600 + jdi;
        const float* xb = &xs[nl0 * 240 + hi * 60];
        #pragma unroll 2
        for (int i = 0; i < 60; ++i) {
            float xv0 = xb[i], xv1 = xb[240 + i], xv2 = xb[480 + i], xv3 = xb[720 + i];
            float4 w;
            w = *(const float4*)&wq[i * 60];
            aq[0].x += xv0*w.x; aq[0].y += xv0*w.y; aq[0].z += xv0*w.z; aq[0].w += xv0*w.w;
            aq[1].x += xv1*w.x; aq[1].y += xv1*w.y; aq[1].z += xv1*w.z; aq[1].w += xv1*w.w;
            aq[2].x += xv2*w.x; aq[2].y += xv2*w.y; aq[2].z += xv2*w.z; aq[2].w += xv2*w.w;
            aq[3].x += xv3*w.x; aq[3].y += xv3*w.y; aq[3].z += xv3*w.z; aq[3].w += xv3*w.w;
            w = *(const float4*)&wk[i * 60];
            ak[0].x += xv0*w.x; ak[0].y += xv0*w.y; ak[0].z += xv0*w.z; ak[0].w += xv0*w.w;
            ak[1].x += xv1*w.x; ak[1].y += xv1*w.y; ak[1].z += xv1*w.z; ak[1].w += xv1*w.w;
            ak[2].x += xv2*w.x; ak[2].y += xv2*w.y; ak[2].z += xv2*w.z; ak[2].w += xv2*w.w;
            ak[3].x += xv3*w.x; ak[3].y += xv3*w.y; ak[3].z += xv3*w.z; ak[3].w += xv3*w.w;
            w = *(const float4*)&wv[i * 60];
            av[0].x += xv0*w.x; av[0].y += xv0*w.y; av[0].z += xv0*w.z; av[0].w += xv0*w.w;
            av[1].x += xv1*w.x; av[1].y += xv1*w.y; av[1].z += xv1*w.z; av[1].w += xv1*w.w;
            av[2].x += xv2*w.x; av[2].y += xv2*w.y; av[2].z += xv2*w.z; av[2].w += xv2*w.w;
            av[3].x += xv3*w.x; av[3].y += xv3*w.y; av[3].z += xv3*w.z; av[3].w += xv3*w.w;
        }
    }
    {
        const float* wq = Wqe + he * 6400 + jde;
        const float* wk = Wke + he * 6400 + jde;
        const float* xb = &xs[nl0 * 240 + he * 80];
        #pragma unroll 2
        for (int i = 0; i < 80; ++i) {
            float xv0 = xb[i], xv1 = xb[240 + i], xv2 = xb[480 + i], xv3 = xb[720 + i];
            float4 w;
            w = *(const float4*)&wq[i * 80];
            aqe[0].x += xv0*w.x; aqe[0].y += xv0*w.y; aqe[0].z += xv0*w.z; aqe[0].w += xv0*w.w;
            aqe[1].x += xv1*w.x; aqe[1].y += xv1*w.y; aqe[1].z += xv1*w.z; aqe[1].w += xv1*w.w;
            aqe[2].x += xv2*w.x; aqe[2].y += xv2*w.y; aqe[2].z += xv2*w.z; aqe[2].w += xv2*w.w;
            aqe[3].x += xv3*w.x; aqe[3].y += xv3*w.y; aqe[3].z += xv3*w.z; aqe[3].w += xv3*w.w;
            w = *(const float4*)&wk[i * 80];
            ake[0].x += xv0*w.x; ake[0].y += xv0*w.y; ake[0].z += xv0*w.z; ake[0].w += xv0*w.w;
            ake[1].x += xv1*w.x; ake[1].y += xv1*w.y; ake[1].z += xv1*w.z; ake[1].w += xv1*w.w;
            ake[2].x += xv2*w.x; ake[2].y += xv2*w.y; ake[2].z += xv2*w.z; ake[2].w += xv2*w.w;
            ake[3].x += xv3*w.x; ake[3].y += xv3*w.y; ake[3].z += xv3*w.z; ake[3].w += xv3*w.w;
        }
    }
    #pragma unroll
    for (int n = 0; n < 4; ++n) {
        const int node = base_node + nl0 + n;
        if (node >= N) break;
        const int ob = node * 240 + slot * 4;
        *(float4*)&q_inv[ob] = aq[n];
        *(float4*)&k_inv[ob] = ak[n];
        *(float4*)&v_inv[ob] = av[n];
        *(float4*)&q_ev[ob]  = aqe[n];
        *(float4*)&k_ev[ob]  = ake[n];
    }
}

// ---------------------------------------------------------------------------
// CSR build
// ---------------------------------------------------------------------------
__global__ __launch_bounds__(256) void hist_kernel(
    const int* __restrict__ rcv, int* __restrict__ counts, int E)
{
    int e = blockIdx.x * 256 + threadIdx.x;
    if (e < E) atomicAdd(&counts[rcv[e]], 1);
}

__global__ __launch_bounds__(1024) void scan_kernel(
    const int* __restrict__ counts, int* __restrict__ rowstart,
    int* __restrict__ cursor, int N)
{
    __shared__ int wsum[16];
    __shared__ int carry_s;
    if (threadIdx.x == 0) carry_s = 0;
    __syncthreads();
    const int lane = threadIdx.x & 63;
    const int w    = threadIdx.x >> 6;
    for (int base = 0; base < N; base += 1024) {
        const int i = base + threadIdx.x;
        int v = (i < N) ? counts[i] : 0;
        int x = v;
        #pragma unroll
        for (int off = 1; off < 64; off <<= 1) {
            int t = __shfl_up(x, off);
            if (lane >= off) x += t;
        }
        if (lane == 63) wsum[w] = x;
        __syncthreads();
        if (w == 0) {
            int s = (lane < 16) ? wsum[lane] : 0;
            #pragma unroll
            for (int off = 1; off < 16; off <<= 1) {
                int t = __shfl_up(s, off);
                if (lane >= off) s += t;
            }
            if (lane < 16) wsum[lane] = s;
        }
        __syncthreads();
        const int woff = (w == 0) ? 0 : wsum[w - 1];
        const int ex = carry_s + woff + x - v;
        if (i < N) { rowstart[i] = ex; cursor[i] = ex; }
        __syncthreads();
        if (threadIdx.x == 1023) carry_s += wsum[15];
    }
    __syncthreads();
    if (threadIdx.x == 0) rowstart[N] = carry_s;
}

__global__ __launch_bounds__(256) void scatter_kernel(
    const int* __restrict__ rcv, int* __restrict__ cursor,
    int* __restrict__ csr, int E)
{
    int e = blockIdx.x * 256 + threadIdx.x;
    if (e < E) {
        int pos = atomicAdd(&cursor[rcv[e]], 1);
        csr[pos] = e;
    }
}

// ---------------------------------------------------------------------------
// Alpha kernel: processes edges in CSR (receiver-sorted) order, EPT edges per
// thread so each wave-uniform W ds_read feeds 4*EPT FMAs. Output row i (CSR
// position): [aI0..3, aE0..2, snd_as_float_bits], cutoff folded in.
// ---------------------------------------------------------------------------
__global__ __launch_bounds__(ABLK, 2) void alpha_kernel(
    const float* __restrict__ ev_f, const float* __restrict__ rbf,
    const float* __restrict__ cut,
    const float* __restrict__ Wfi,  const float* __restrict__ bfi,
    const float* __restrict__ Wfe,  const float* __restrict__ bfe,
    const int* __restrict__ snd,    const int* __restrict__ rcv,
    const int* __restrict__ csr,
    const float* __restrict__ q_inv, const float* __restrict__ k_inv,
    const float* __restrict__ q_ev,  const float* __restrict__ k_ev,
    float* __restrict__ alpha, int E)
{
    __shared__ float WI[35 * 240];
    __shared__ float WE[35 * 240];
    __shared__ float BI[240];
    __shared__ float BE[240];
    for (int idx = threadIdx.x; idx < 35 * 240; idx += ABLK) {
        WI[idx] = Wfi[idx];
        WE[idx] = Wfe[idx];
    }
    for (int idx = threadIdx.x; idx < 240; idx += ABLK) {
        BI[idx] = bfi[idx];
        BE[idx] = bfe[idx];
    }
    __syncthreads();

    const float s60 = 0.12909944487358056f;  // 1/sqrt(60)
    const float s80 = 0.11180339887498948f;  // 1/sqrt(80)

    const int base = blockIdx.x * (ABLK * EPT);

    int ii[EPT], sN[EPT], rN[EPT];
    float cc[EPT];
    float f[EPT][35];
    #pragma unroll
    for (int t = 0; t < EPT; ++t) {
        int i = base + t * ABLK + threadIdx.x;
        if (i >= E) i = E - 1;               // clamp: duplicate same-value write
        ii[t] = i;
        const int e = csr[i];
        sN[t] = snd[e]; rN[t] = rcv[e]; cc[t] = cut[e];
        const float4* rb = (const float4*)(rbf + (size_t)e * 32);
        #pragma unroll
        for (int k4 = 0; k4 < 8; ++k4) {
            float4 v = rb[k4];
            f[t][k4*4+0] = v.x; f[t][k4*4+1] = v.y;
            f[t][k4*4+2] = v.z; f[t][k4*4+3] = v.w;
        }
        const float* es = ev_f + (size_t)sN[t] * 15;
        const float* er = ev_f + (size_t)rN[t] * 15;
        float i0 = 0.f, i1 = 0.f, i2 = 0.f;
        #pragma unroll
        for (int q = 0; q < 3; ++q)  { float d = es[q] - er[q]; i0 += d * d; }
        #pragma unroll
        for (int q = 3; q < 8; ++q)  { float d = es[q] - er[q]; i1 += d * d; }
        #pragma unroll
        for (int q = 8; q < 15; ++q) { float d = es[q] - er[q]; i2 += d * d; }
        f[t][32] = i0; f[t][33] = i1; f[t][34] = i2;
    }

    float out[EPT][8];

    // ---- invariant heads ----
    #pragma unroll
    for (int h = 0; h < 4; ++h) {
        float acc[EPT];
        #pragma unroll
        for (int t = 0; t < EPT; ++t) acc[t] = 0.f;
        #pragma unroll 1
        for (int j4 = 0; j4 < 15; ++j4) {
            const int j = h * 60 + j4 * 4;
            const float4 b4 = *(const float4*)&BI[j];
            float4 fw[EPT];
            #pragma unroll
            for (int t = 0; t < EPT; ++t) fw[t] = b4;
            #pragma unroll
            for (int k = 0; k < 35; ++k) {
                const float4 w = *(const float4*)&WI[k * 240 + j];
                #pragma unroll
                for (int t = 0; t < EPT; ++t) {
                    const float fv = f[t][k];
                    fw[t].x += fv * w.x; fw[t].y += fv * w.y;
                    fw[t].z += fv * w.z; fw[t].w += fv * w.w;
                }
            }
            #pragma unroll
            for (int t = 0; t < EPT; ++t) {
                const float4 q  = *(const float4*)(q_inv + (size_t)rN[t] * 240 + j);
                const float4 kk = *(const float4*)(k_inv + (size_t)sN[t] * 240 + j);
                acc[t] += q.x * kk.x * fw[t].x + q.y * kk.y * fw[t].y
                        + q.z * kk.z * fw[t].z + q.w * kk.w * fw[t].w;
            }
        }
        #pragma unroll
        for (int t = 0; t < EPT; ++t) out[t][h] = acc[t] * s60 * cc[t];
    }

    // ---- equivariant heads ----
    #pragma unroll
    for (int h = 0; h < 3; ++h) {
        float acc[EPT];
        #pragma unroll
        for (int t = 0; t < EPT; ++t) acc[t] = 0.f;
        #pragma unroll 1
        for (int j4 = 0; j4 < 20; ++j4) {
            const int j = h * 80 + j4 * 4;
            const float4 b4 = *(const float4*)&BE[j];
            float4 fw[EPT];
            #pragma unroll
            for (int t = 0; t < EPT; ++t) fw[t] = b4;
            #pragma unroll
            for (int k = 0; k < 35; ++k) {
                const float4 w = *(const float4*)&WE[k * 240 + j];
                #pragma unroll
                for (int t = 0; t < EPT; ++t) {
                    const float fv = f[t][k];
                    fw[t].x += fv * w.x; fw[t].y += fv * w.y;
                    fw[t].z += fv * w.z; fw[t].w += fv * w.w;
                }
            }
            #pragma unroll
            for (int t = 0; t < EPT; ++t) {
                const float4 q  = *(const float4*)(q_ev + (size_t)rN[t] * 240 + j);
                const float4 kk = *(const float4*)(k_ev + (size_t)sN[t] * 240 + j);
                acc[t] += q.x * kk.x * fw[t].x + q.y * kk.y * fw[t].y
                        + q.z * kk.z * fw[t].z + q.w * kk.w * fw[t].w;
            }
        }
        #pragma unroll
        for (int t = 0; t < EPT; ++t) out[t][4 + h] = acc[t] * s80 * cc[t];
    }

    #pragma unroll
    for (int t = 0; t < EPT; ++t) {
        out[t][7] = __int_as_float(sN[t]);
        float4* ap = (float4*)(alpha + (size_t)ii[t] * 8);
        ap[0] = make_float4(out[t][0], out[t][1], out[t][2], out[t][3]);
        ap[1] = make_float4(out[t][4], out[t][5], out[t][6], out[t][7]);
    }
}

// ---------------------------------------------------------------------------
// Gather kernel: one block per receiver. Stages per-chunk edge metadata in
// LDS (alpha rows are CSR-sequential -> coalesced), then accumulates.
// ---------------------------------------------------------------------------
__global__ __launch_bounds__(256) void gather_kernel(
    const int* __restrict__ rowstart, const int* __restrict__ csr,
    const float* __restrict__ alpha,
    const float* __restrict__ v_inv, const float* __restrict__ sh,
    float* __restrict__ dinv, float* __restrict__ dev)
{
    const int r = blockIdx.x;
    const int c = threadIdx.x;
    const int beg = rowstart[r], end = rowstart[r + 1];

    __shared__ float sal[64][8];
    __shared__ int   sed[64];

    float acc = 0.f;
    for (int chunk = beg; chunk < end; chunk += 64) {
        const int len = min(64, end - chunk);
        __syncthreads();
        if (c < len) {
            const float4* ap = (const float4*)(alpha + (size_t)(chunk + c) * 8);
            const float4 a0 = ap[0], a1 = ap[1];
            *(float4*)&sal[c][0] = a0;
            *(float4*)&sal[c][4] = a1;
            sed[c] = csr[chunk + c];
        }
        __syncthreads();
        if (c < 240) {
            const int h = c / 60;
            #pragma unroll 4
            for (int i = 0; i < len; ++i) {
                const int s = __float_as_int(sal[i][7]);
                acc += sal[i][h] * v_inv[(size_t)s * 240 + c];
            }
        } else if (c < 255) {
            const int i0 = c - 240;
            const int h = (i0 < 3) ? 4 : ((i0 < 8) ? 5 : 6);
            for (int i = 0; i < len; ++i)
                acc += sal[i][h] * sh[(size_t)sed[i] * 15 + i0];
        }
    }
    if (c < 240) dinv[(size_t)r * 240 + c] = acc;
    else if (c < 255) dev[(size_t)r * 15 + (c - 240)] = acc;
}

extern "C" void kernel_launch(void* const* d_in, const int* in_sizes, int n_in,
                              void* d_out, int out_size, void* d_ws, size_t ws_size,
                              hipStream_t stream) {
    const float* inv_f = (const float*)d_in[0];
    const float* ev_f  = (const float*)d_in[1];
    const float* rbf   = (const float*)d_in[2];
    const float* sh    = (const float*)d_in[3];
    const float* cut   = (const float*)d_in[4];
    const float* Wq    = (const float*)d_in[5];
    const float* Wk    = (const float*)d_in[6];
    const float* Wv    = (const float*)d_in[7];
    const float* Wqe   = (const float*)d_in[8];
    const float* Wke   = (const float*)d_in[9];
    const float* Wfi   = (const float*)d_in[10];
    const float* bfi   = (const float*)d_in[11];
    const float* Wfe   = (const float*)d_in[12];
    const float* bfe   = (const float*)d_in[13];
    const int*   snd   = (const int*)d_in[14];
    const int*   rcv   = (const int*)d_in[15];

    const int N = in_sizes[0] / 240;
    const int E = in_sizes[14];

    float* out  = (float*)d_out;
    float* dinv = out;                       // [N,240]
    float* dev  = out + (size_t)N * 240;     // [N,15]

    float* ws = (float*)d_ws;
    const size_t Nf = (size_t)N * 240;
    float* q_inv = ws + 0 * Nf;
    float* k_inv = ws + 1 * Nf;
    float* v_inv = ws + 2 * Nf;
    float* q_ev  = ws + 3 * Nf;
    float* k_ev  = ws + 4 * Nf;
    float* alpha = ws + 5 * Nf;                           // E*8 floats
    int*   ibase    = (int*)(alpha + (size_t)E * 8);
    int*   counts   = ibase;                              // N
    int*   rowstart = ibase + N;                          // N+1
    int*   cursor   = ibase + 2 * N + 1;                  // N
    int*   csr      = ibase + 3 * N + 1;                  // E

    hipMemsetAsync(counts, 0, (size_t)N * sizeof(int), stream);

    proj_kernel<<<(N + PNPB - 1) / PNPB, 256, 0, stream>>>(
        inv_f, Wq, Wk, Wv, Wqe, Wke, q_inv, k_inv, v_inv, q_ev, k_ev, N);

    const int eb = (E + 255) / 256;
    hist_kernel<<<eb, 256, 0, stream>>>(rcv, counts, E);
    scan_kernel<<<1, 1024, 0, stream>>>(counts, rowstart, cursor, N);
    scatter_kernel<<<eb, 256, 0, stream>>>(rcv, cursor, csr, E);

    const int ab = (E + ABLK * EPT - 1) / (ABLK * EPT);
    alpha_kernel<<<ab, ABLK, 0, stream>>>(
        ev_f, rbf, cut, Wfi, bfi, Wfe, bfe, snd, rcv, csr,
        q_inv, k_inv, q_ev, k_ev, alpha, E);

    gather_kernel<<<N, 256, 0, stream>>>(
        rowstart, csr, alpha, v_inv, sh, dinv, dev);
}